// Round 10
// baseline (106.229 us; speedup 1.0000x reference)
//
#include <hip/hip_runtime.h>

#define D1 96
#define GRID_VOX (D1 * D1 * D1)
#define CAP1B 2048  // per-block conv1 pairs (max 64*26=1664 exact)
#define CAP2B 512   // per-(block,s) conv2 pairs (max 64*7=448 exact)

typedef __attribute__((ext_vector_type(8))) short short8_t;  // 8 bf16
typedef __attribute__((ext_vector_type(4))) float f32x4;

__device__ __forceinline__ unsigned short bf16rne(float x) {
    unsigned u = __float_as_uint(x);
    return (unsigned short)((u + 0x7FFF + ((u >> 16) & 1)) >> 16);
}
__device__ __forceinline__ void split2(float v, unsigned short& hi,
                                       unsigned short& lo) {
    hi = bf16rne(v);
    float hf = __uint_as_float((unsigned)hi << 16);
    lo = bf16rne(v - hf);
}

// ---------------------------------------------------------------------------
// setup: blocks [0,432) zero grid; block 432 zeros pair counters;
// blocks [433,1475) pack MFMA B-fragments + fold fixup weights.
// ---------------------------------------------------------------------------
__global__ void setup_kernel(const float* __restrict__ W1,
                             const float* __restrict__ W2,
                             int4* __restrict__ grid16,
                             int* __restrict__ cnts, int ncnt,
                             unsigned short* __restrict__ Wpk1h,
                             unsigned short* __restrict__ Wpk1l,
                             unsigned short* __restrict__ Wpk2h,
                             unsigned short* __restrict__ Wpk2l,
                             float* __restrict__ W2e) {
    int b = blockIdx.x;
    if (b < 432) {
        grid16[b * 256 + threadIdx.x] = make_int4(0, 0, 0, 0);
        return;
    }
    if (b == 432) {
        for (int u = threadIdx.x; u < ncnt; u += 256) cnts[u] = 0;
        return;
    }
    int t = (b - 433) * 256 + threadIdx.x;
    if (t < 512) {  // conv1 B-fragments: W1[13] self tap
        int fid = t >> 6, l = t & 63;
        int kb = fid >> 2, c = fid & 3;
#pragma unroll
        for (int e = 0; e < 8; ++e) {
            int ci = kb * 32 + ((l >> 4) << 3) + e;
            int co = c * 16 + (l & 15);
            unsigned short hi, lo;
            split2(W1[13 * 4096 + ci * 64 + co], hi, lo);
            Wpk1h[(size_t)t * 8 + e] = hi;
            Wpk1l[(size_t)t * 8 + e] = lo;
        }
    } else if (t < 512 + 4096) {  // conv2 dense (self-parent fold) fragments
        int u = t - 512;
        int fid = u >> 6, l = u & 63;
        int s = fid >> 3, kb = (fid >> 2) & 1, c = fid & 3;
        int s0 = (s >> 2) & 1, s1 = (s >> 1) & 1, s2 = s & 1;
#pragma unroll
        for (int e = 0; e < 8; ++e) {
            int ci = kb * 32 + ((l >> 4) << 3) + e;
            int co = c * 16 + (l & 15);
            float sum = 0.f;
            for (int o0 = -s0; o0 <= 1 - s0; ++o0)
                for (int o1 = -s1; o1 <= 1 - s1; ++o1)
                    for (int o2 = -s2; o2 <= 1 - s2; ++o2) {
                        int k = (o0 + 1) * 9 + (o1 + 1) * 3 + (o2 + 1);
                        sum += W2[k * 4096 + ci * 64 + co];
                    }
            unsigned short hi, lo;
            split2(sum, hi, lo);
            Wpk2h[(size_t)u * 8 + e] = hi;
            Wpk2l[(size_t)u * 8 + e] = lo;
        }
    } else {  // W2e fp32 fixup weights
        int r = t - 4608;
        if (r >= 64 * 4096) return;
        int sd = r >> 12, e = r & 4095;
        int s = sd >> 3, d = sd & 7;
        int sa[3] = { (s >> 2) & 1, (s >> 1) & 1, s & 1 };
        int da[3] = { (d >> 2) & 1, (d >> 1) & 1, d & 1 };
        int lo_[3], hi_[3];
        for (int a = 0; a < 3; ++a) {
            int p = sa[a] - 1 + da[a];
            int l = 2 * p - sa[a];     if (l < -1) l = -1;
            int h = 2 * p + 1 - sa[a]; if (h > 1) h = 1;
            lo_[a] = l; hi_[a] = h;
        }
        float sum = 0.f;
        for (int o0 = lo_[0]; o0 <= hi_[0]; ++o0)
            for (int o1 = lo_[1]; o1 <= hi_[1]; ++o1)
                for (int o2 = lo_[2]; o2 <= hi_[2]; ++o2) {
                    int k = (o0 + 1) * 9 + (o1 + 1) * 3 + (o2 + 1);
                    sum += W2[k * 4096 + e];
                }
        W2e[(size_t)sd * 4096 + e] = sum;
    }
}

// ---------------------------------------------------------------------------
__global__ void scatter_grid_kernel(const int* __restrict__ coords,
                                    unsigned short* __restrict__ grid, int n) {
    int i = blockIdx.x * blockDim.x + threadIdx.x;
    if (i < n)
        grid[(coords[3 * i] * D1 + coords[3 * i + 1]) * D1 + coords[3 * i + 2]] =
            (unsigned short)(i + 1);
}

// ---------------------------------------------------------------------------
// Pair builder: appends straight into per-block64 (conv1) and per-(block64,s)
// (conv2) lists. entry = j | tag<<17 | row<<23  (row = i & 63).
// ---------------------------------------------------------------------------
__global__ void build_pairs_kernel(const int* __restrict__ coords,
                                   const unsigned short* __restrict__ grid,
                                   int* __restrict__ c1b, int* __restrict__ p1b,
                                   int* __restrict__ c2b, int* __restrict__ p2b,
                                   int n) {
    int i = blockIdx.x * blockDim.x + threadIdx.x;
    if (i >= n) return;
    int blk = i >> 6, l = i & 63;
    int c0 = coords[3 * i], cc1 = coords[3 * i + 1], cc2 = coords[3 * i + 2];

    int jv[27];
#pragma unroll
    for (int k = 0; k < 27; ++k) {
        int o0 = k / 9 - 1, o1 = (k / 3) % 3 - 1, o2 = k % 3 - 1;
        int x0 = c0 + o0, x1 = cc1 + o1, x2 = cc2 + o2;
        bool inb = (unsigned)x0 < D1 && (unsigned)x1 < D1 && (unsigned)x2 < D1;
        jv[k] = inb ? (int)grid[(x0 * D1 + x1) * D1 + x2] - 1 : -1;
    }

#pragma unroll
    for (int k = 0; k < 27; ++k) {
        if (k == 13) continue;
        int j = jv[k];
        if (j < 0) continue;
        int o0 = k / 9 - 1, o1 = (k / 3) % 3 - 1, o2 = k % 3 - 1;
        int slot = atomicAdd(&c1b[blk], 1);
        p1b[(size_t)blk * CAP1B + slot] = j | (k << 17) | (l << 23);
#pragma unroll
        for (int s = 0; s < 8; ++s) {
            int d0 = o0 + 1 - ((s >> 2) & 1);
            int d1 = o1 + 1 - ((s >> 1) & 1);
            int d2 = o2 + 1 - (s & 1);
            if (((d0 | d1 | d2) & ~1) == 0) {
                int d = (d0 << 2) | (d1 << 1) | d2;
                int sl = atomicAdd(&c2b[blk * 8 + s], 1);
                p2b[((size_t)blk * 8 + s) * CAP2B + sl] = j | (d << 17) | (l << 23);
            }
        }
    }
}

// ---------------------------------------------------------------------------
__device__ __forceinline__ void load_split_A(const float* __restrict__ src,
                                             int arow, int lane, short8_t& ah0,
                                             short8_t& al0, short8_t& ah1,
                                             short8_t& al1) {
    const float* ap = src + (size_t)arow * 64 + ((lane >> 4) << 3);
    f32x4 a0 = *(const f32x4*)(ap);
    f32x4 a1 = *(const f32x4*)(ap + 4);
    f32x4 a2 = *(const f32x4*)(ap + 32);
    f32x4 a3 = *(const f32x4*)(ap + 36);
#pragma unroll
    for (int e = 0; e < 4; ++e) {
        unsigned short hh, ll;
        split2(a0[e], hh, ll); ah0[e] = (short)hh; al0[e] = (short)ll;
        split2(a1[e], hh, ll); ah0[4 + e] = (short)hh; al0[4 + e] = (short)ll;
        split2(a2[e], hh, ll); ah1[e] = (short)hh; al1[e] = (short)ll;
        split2(a3[e], hh, ll); ah1[4 + e] = (short)hh; al1[4 + e] = (short)ll;
    }
}

// ---------------------------------------------------------------------------
// wave w: rows [16w,16w+16) x 64 cols, 24 MFMAs (hi/lo), +bias -> oT.
// ---------------------------------------------------------------------------
__device__ __forceinline__ void dense_mfma(const short8_t ah0, const short8_t al0,
                                           const short8_t ah1, const short8_t al1,
                                           const short8_t* __restrict__ Bh,
                                           const short8_t* __restrict__ Bl,
                                           const float* __restrict__ bias,
                                           float* __restrict__ oT, int w,
                                           int lane) {
#pragma unroll 1
    for (int c = 0; c < 4; ++c) {
        short8_t bh0 = Bh[c * 64 + lane];
        short8_t bl0 = Bl[c * 64 + lane];
        short8_t bh1 = Bh[(4 + c) * 64 + lane];
        short8_t bl1 = Bl[(4 + c) * 64 + lane];
        f32x4 acc = {0.f, 0.f, 0.f, 0.f};
        acc = __builtin_amdgcn_mfma_f32_16x16x32_bf16(ah0, bh0, acc, 0, 0, 0);
        acc = __builtin_amdgcn_mfma_f32_16x16x32_bf16(al0, bh0, acc, 0, 0, 0);
        acc = __builtin_amdgcn_mfma_f32_16x16x32_bf16(ah0, bl0, acc, 0, 0, 0);
        acc = __builtin_amdgcn_mfma_f32_16x16x32_bf16(ah1, bh1, acc, 0, 0, 0);
        acc = __builtin_amdgcn_mfma_f32_16x16x32_bf16(al1, bh1, acc, 0, 0, 0);
        acc = __builtin_amdgcn_mfma_f32_16x16x32_bf16(ah1, bl1, acc, 0, 0, 0);
        int col = c * 16 + (lane & 15);
        float bb = bias[col];
#pragma unroll
        for (int r = 0; r < 4; ++r) {
            int row = w * 16 + ((lane >> 4) << 2) + r;
            oT[row * 64 + col] = acc[r] + bb;
        }
    }
}

// fixup: one pair, lane = out channel; fj uniform (scalar), wk coalesced vector
__device__ __forceinline__ void fixup_pair(const float* __restrict__ fj,
                                           const float* __restrict__ wk,
                                           float* __restrict__ oT, int l,
                                           int lane) {
    float a0 = 0.f, a1 = 0.f, a2 = 0.f, a3 = 0.f;
#pragma unroll
    for (int c4 = 0; c4 < 16; ++c4) {
        f32x4 fv = *(const f32x4*)(fj + c4 * 4);
        a0 += fv[0] * wk[(c4 * 4 + 0) * 64 + lane];
        a1 += fv[1] * wk[(c4 * 4 + 1) * 64 + lane];
        a2 += fv[2] * wk[(c4 * 4 + 2) * 64 + lane];
        a3 += fv[3] * wk[(c4 * 4 + 3) * 64 + lane];
    }
    atomicAdd(&oT[l * 64 + lane], (a0 + a1) + (a2 + a3));
}

// ---------------------------------------------------------------------------
__global__ __launch_bounds__(256) void conv1_fused_kernel(
    const float* __restrict__ feats, const float* __restrict__ W1,
    const unsigned short* __restrict__ Wpk1h,
    const unsigned short* __restrict__ Wpk1l, const float* __restrict__ b1,
    const int* __restrict__ c1b, const int* __restrict__ p1b,
    float* __restrict__ h, int n) {
    __shared__ __align__(16) float oT[4096];
    int blk = blockIdx.x, base = blk * 64;
    int t = threadIdx.x, w = t >> 6, lane = t & 63;

    int np = c1b[blk];  // uniform
    const int* plist = p1b + (size_t)blk * CAP1B;

    int arow = base + w * 16 + (lane & 15);
    if (arow >= n) arow = n - 1;
    short8_t ah0, al0, ah1, al1;
    load_split_A(feats, arow, lane, ah0, al0, ah1, al1);
    dense_mfma(ah0, al0, ah1, al1, (const short8_t*)Wpk1h,
               (const short8_t*)Wpk1l, b1, oT, w, lane);
    __syncthreads();

#pragma unroll 2
    for (int p = w; p < np; p += 4) {
        int se = __builtin_amdgcn_readfirstlane(plist[p]);
        int j = se & 0x1FFFF, k = (se >> 17) & 31, l = (se >> 23) & 63;
        fixup_pair(feats + (size_t)j * 64, W1 + (size_t)k * 4096, oT, l, lane);
    }
    __syncthreads();

    {  // SiLU + coalesced store
        int r = t >> 2, q0 = (t & 3) * 16;
        if (base + r < n) {
#pragma unroll
            for (int jj = 0; jj < 4; ++jj) {
                f32x4 v = *(f32x4*)&oT[r * 64 + q0 + jj * 4];
#pragma unroll
                for (int u = 0; u < 4; ++u) v[u] = v[u] / (1.f + __expf(-v[u]));
                *(f32x4*)&h[(size_t)(base + r) * 64 + q0 + jj * 4] = v;
            }
        }
    }
}

// ---------------------------------------------------------------------------
// conv2: grid (nblk, 8). Block = 64 parents x 1 child. 2 barriers total.
// ---------------------------------------------------------------------------
__global__ __launch_bounds__(256) void conv2_fused_kernel(
    const float* __restrict__ h, const unsigned short* __restrict__ Wpk2h,
    const unsigned short* __restrict__ Wpk2l, const float* __restrict__ W2e,
    const float* __restrict__ b2, const int* __restrict__ c2b,
    const int* __restrict__ p2b, float* __restrict__ out, int n) {
    __shared__ __align__(16) float oT[4096];
    int blk = blockIdx.x, base = blk * 64, s = blockIdx.y;
    int t = threadIdx.x, w = t >> 6, lane = t & 63;

    int np = c2b[blk * 8 + s];  // uniform
    const int* plist = p2b + ((size_t)blk * 8 + s) * CAP2B;

    int arow = base + w * 16 + (lane & 15);
    if (arow >= n) arow = n - 1;
    short8_t ah0, al0, ah1, al1;
    load_split_A(h, arow, lane, ah0, al0, ah1, al1);
    dense_mfma(ah0, al0, ah1, al1,
               (const short8_t*)Wpk2h + (size_t)s * 8 * 64,
               (const short8_t*)Wpk2l + (size_t)s * 8 * 64, b2, oT, w, lane);
    __syncthreads();

#pragma unroll 2
    for (int p = w; p < np; p += 4) {
        int se = __builtin_amdgcn_readfirstlane(plist[p]);
        int j = se & 0x1FFFF, d = (se >> 17) & 31, l = (se >> 23) & 63;
        fixup_pair(h + (size_t)j * 64, W2e + (size_t)(s * 8 + d) * 4096, oT, l,
                   lane);
    }
    __syncthreads();

    {  // SiLU + store (out row = parent*8 + s)
        int r = t >> 2, q0 = (t & 3) * 16;
        if (base + r < n) {
#pragma unroll
            for (int jj = 0; jj < 4; ++jj) {
                f32x4 v = *(f32x4*)&oT[r * 64 + q0 + jj * 4];
#pragma unroll
                for (int u = 0; u < 4; ++u) v[u] = v[u] / (1.f + __expf(-v[u]));
                *(f32x4*)&out[((size_t)(base + r) * 8 + s) * 64 + q0 + jj * 4] = v;
            }
        }
    }
}

// ---------------------------------------------------------------------------
extern "C" void kernel_launch(void* const* d_in, const int* in_sizes, int n_in,
                              void* d_out, int out_size, void* d_ws,
                              size_t ws_size, hipStream_t stream) {
    const int* coords = (const int*)d_in[0];
    const float* feats = (const float*)d_in[1];
    const float* W1 = (const float*)d_in[2];
    const float* b1 = (const float*)d_in[3];
    const float* W2 = (const float*)d_in[4];
    const float* b2 = (const float*)d_in[5];
    float* out = (float*)d_out;

    int n = in_sizes[0] / 3;  // 20000
    int nblk = (n + 63) / 64; // 313

    char* ws = (char*)d_ws;
    size_t off = 0;
    auto alloc = [&](size_t bytes) {
        size_t o = off;
        off = (off + bytes + 255) & ~(size_t)255;
        return o;
    };
    unsigned short* grid1 = (unsigned short*)(ws + alloc((size_t)GRID_VOX * 2));
    float* h      = (float*)(ws + alloc((size_t)n * 64 * 4));      // 5.12 MB
    float* W2e    = (float*)(ws + alloc(64 * 4096 * 4));           // 1 MB
    unsigned short* Wpk1h = (unsigned short*)(ws + alloc(512 * 8 * 2));
    unsigned short* Wpk1l = (unsigned short*)(ws + alloc(512 * 8 * 2));
    unsigned short* Wpk2h = (unsigned short*)(ws + alloc(4096 * 8 * 2));
    unsigned short* Wpk2l = (unsigned short*)(ws + alloc(4096 * 8 * 2));
    int*   c1b    = (int*)(ws + alloc((size_t)nblk * 9 * 4));      // c1b + c2b
    int*   c2b    = c1b + nblk;
    int*   p1b    = (int*)(ws + alloc((size_t)nblk * CAP1B * 4));  // 2.56 MB
    int*   p2b    = (int*)(ws + alloc((size_t)nblk * 8 * CAP2B * 4)); // 5.1 MB

    // setup: 432 grid-fill + 1 counter-fill + 1042 weight-prep blocks
    setup_kernel<<<1475, 256, 0, stream>>>(W1, W2, (int4*)grid1, c1b, nblk * 9,
                                           Wpk1h, Wpk1l, Wpk2h, Wpk2l, W2e);
    scatter_grid_kernel<<<(n + 255) / 256, 256, 0, stream>>>(coords, grid1, n);
    build_pairs_kernel<<<(n + 255) / 256, 256, 0, stream>>>(
        coords, grid1, c1b, p1b, c2b, p2b, n);

    conv1_fused_kernel<<<nblk, 256, 0, stream>>>(feats, W1, Wpk1h, Wpk1l, b1,
                                                 c1b, p1b, h, n);
    conv2_fused_kernel<<<dim3(nblk, 8), 256, 0, stream>>>(
        h, Wpk2h, Wpk2l, W2e, b2, c2b, p2b, out, n);
}

// Round 11
// 88.182 us; speedup vs baseline: 1.2047x; 1.2047x over previous
//
#include <hip/hip_runtime.h>

#define D1 96
#define GRID_VOX (D1 * D1 * D1)
#define CAP1 32   // per-voxel conv1 pairs (max 26 exact)
#define CAP2S 8   // per-(voxel,s) conv2 pairs (max 7 exact)

typedef __attribute__((ext_vector_type(8))) short short8_t;  // 8 bf16
typedef __attribute__((ext_vector_type(4))) float f32x4;

__device__ __forceinline__ unsigned short bf16rne(float x) {
    unsigned u = __float_as_uint(x);
    return (unsigned short)((u + 0x7FFF + ((u >> 16) & 1)) >> 16);
}
__device__ __forceinline__ void split2(float v, unsigned short& hi,
                                       unsigned short& lo) {
    hi = bf16rne(v);
    float hf = __uint_as_float((unsigned)hi << 16);
    lo = bf16rne(v - hf);
}

// ---------------------------------------------------------------------------
// setup: blocks [0,432) zero grid; blocks [432,1474) pack MFMA B-fragments
// (bf16 hi/lo) and fold fp32 fixup weights.
// ---------------------------------------------------------------------------
__global__ void setup_kernel(const float* __restrict__ W1,
                             const float* __restrict__ W2,
                             int4* __restrict__ grid16,
                             unsigned short* __restrict__ Wpk1h,
                             unsigned short* __restrict__ Wpk1l,
                             unsigned short* __restrict__ Wpk2h,
                             unsigned short* __restrict__ Wpk2l,
                             float* __restrict__ W2e) {
    int b = blockIdx.x;
    if (b < 432) {
        grid16[b * 256 + threadIdx.x] = make_int4(0, 0, 0, 0);
        return;
    }
    int t = (b - 432) * 256 + threadIdx.x;
    if (t < 512) {  // conv1 B-fragments: W1[13] self tap
        int fid = t >> 6, l = t & 63;
        int kb = fid >> 2, c = fid & 3;
#pragma unroll
        for (int e = 0; e < 8; ++e) {
            int ci = kb * 32 + ((l >> 4) << 3) + e;
            int co = c * 16 + (l & 15);
            unsigned short hi, lo;
            split2(W1[13 * 4096 + ci * 64 + co], hi, lo);
            Wpk1h[(size_t)t * 8 + e] = hi;
            Wpk1l[(size_t)t * 8 + e] = lo;
        }
    } else if (t < 512 + 4096) {  // conv2 dense (self-parent fold) fragments
        int u = t - 512;
        int fid = u >> 6, l = u & 63;
        int s = fid >> 3, kb = (fid >> 2) & 1, c = fid & 3;
        int s0 = (s >> 2) & 1, s1 = (s >> 1) & 1, s2 = s & 1;
#pragma unroll
        for (int e = 0; e < 8; ++e) {
            int ci = kb * 32 + ((l >> 4) << 3) + e;
            int co = c * 16 + (l & 15);
            float sum = 0.f;
            for (int o0 = -s0; o0 <= 1 - s0; ++o0)
                for (int o1 = -s1; o1 <= 1 - s1; ++o1)
                    for (int o2 = -s2; o2 <= 1 - s2; ++o2) {
                        int k = (o0 + 1) * 9 + (o1 + 1) * 3 + (o2 + 1);
                        sum += W2[k * 4096 + ci * 64 + co];
                    }
            unsigned short hi, lo;
            split2(sum, hi, lo);
            Wpk2h[(size_t)u * 8 + e] = hi;
            Wpk2l[(size_t)u * 8 + e] = lo;
        }
    } else {  // W2e fp32 fixup weights
        int r = t - 4608;
        if (r >= 64 * 4096) return;
        int sd = r >> 12, e = r & 4095;
        int s = sd >> 3, d = sd & 7;
        int sa[3] = { (s >> 2) & 1, (s >> 1) & 1, s & 1 };
        int da[3] = { (d >> 2) & 1, (d >> 1) & 1, d & 1 };
        int lo_[3], hi_[3];
        for (int a = 0; a < 3; ++a) {
            int p = sa[a] - 1 + da[a];
            int l = 2 * p - sa[a];     if (l < -1) l = -1;
            int h = 2 * p + 1 - sa[a]; if (h > 1) h = 1;
            lo_[a] = l; hi_[a] = h;
        }
        float sum = 0.f;
        for (int o0 = lo_[0]; o0 <= hi_[0]; ++o0)
            for (int o1 = lo_[1]; o1 <= hi_[1]; ++o1)
                for (int o2 = lo_[2]; o2 <= hi_[2]; ++o2) {
                    int k = (o0 + 1) * 9 + (o1 + 1) * 3 + (o2 + 1);
                    sum += W2[k * 4096 + e];
                }
        W2e[(size_t)sd * 4096 + e] = sum;
    }
}

// ---------------------------------------------------------------------------
__global__ void scatter_grid_kernel(const int* __restrict__ coords,
                                    unsigned short* __restrict__ grid, int n) {
    int i = blockIdx.x * blockDim.x + threadIdx.x;
    if (i < n)
        grid[(coords[3 * i] * D1 + coords[3 * i + 1]) * D1 + coords[3 * i + 2]] =
            (unsigned short)(i + 1);
}

// ---------------------------------------------------------------------------
// Per-voxel pair builder (no atomics). conv1: j|(k<<17); conv2: j|(d<<17).
// ---------------------------------------------------------------------------
__global__ void build_pairs_kernel(const int* __restrict__ coords,
                                   const unsigned short* __restrict__ grid,
                                   int* __restrict__ c1, int* __restrict__ p1,
                                   int* __restrict__ c2s, int* __restrict__ p2s,
                                   int n) {
    int i = blockIdx.x * blockDim.x + threadIdx.x;
    if (i >= n) return;
    int c0 = coords[3 * i], cc1 = coords[3 * i + 1], cc2 = coords[3 * i + 2];

    int jv[27];
#pragma unroll
    for (int k = 0; k < 27; ++k) {
        int o0 = k / 9 - 1, o1 = (k / 3) % 3 - 1, o2 = k % 3 - 1;
        int x0 = c0 + o0, x1 = cc1 + o1, x2 = cc2 + o2;
        bool inb = (unsigned)x0 < D1 && (unsigned)x1 < D1 && (unsigned)x2 < D1;
        jv[k] = inb ? (int)grid[(x0 * D1 + x1) * D1 + x2] - 1 : -1;
    }

    int n1 = 0;
    int n2[8] = {0, 0, 0, 0, 0, 0, 0, 0};
#pragma unroll
    for (int k = 0; k < 27; ++k) {
        if (k == 13) continue;
        int j = jv[k];
        if (j < 0) continue;
        int o0 = k / 9 - 1, o1 = (k / 3) % 3 - 1, o2 = k % 3 - 1;
        p1[(size_t)i * CAP1 + n1] = j | (k << 17);
        ++n1;
#pragma unroll
        for (int s = 0; s < 8; ++s) {
            int d0 = o0 + 1 - ((s >> 2) & 1);
            int d1 = o1 + 1 - ((s >> 1) & 1);
            int d2 = o2 + 1 - (s & 1);
            if (((d0 | d1 | d2) & ~1) == 0) {
                int d = (d0 << 2) | (d1 << 1) | d2;
                p2s[((size_t)i * 8 + s) * CAP2S + n2[s]] = j | (d << 17);
                ++n2[s];
            }
        }
    }
    c1[i] = n1;
#pragma unroll
    for (int s = 0; s < 8; ++s) c2s[i * 8 + s] = n2[s];
}

// ---------------------------------------------------------------------------
__device__ __forceinline__ void load_split_A(const float* __restrict__ src,
                                             int arow, int lane, short8_t& ah0,
                                             short8_t& al0, short8_t& ah1,
                                             short8_t& al1) {
    const float* ap = src + (size_t)arow * 64 + ((lane >> 4) << 3);
    f32x4 a0 = *(const f32x4*)(ap);
    f32x4 a1 = *(const f32x4*)(ap + 4);
    f32x4 a2 = *(const f32x4*)(ap + 32);
    f32x4 a3 = *(const f32x4*)(ap + 36);
#pragma unroll
    for (int e = 0; e < 4; ++e) {
        unsigned short hh, ll;
        split2(a0[e], hh, ll); ah0[e] = (short)hh; al0[e] = (short)ll;
        split2(a1[e], hh, ll); ah0[4 + e] = (short)hh; al0[4 + e] = (short)ll;
        split2(a2[e], hh, ll); ah1[e] = (short)hh; al1[e] = (short)ll;
        split2(a3[e], hh, ll); ah1[4 + e] = (short)hh; al1[4 + e] = (short)ll;
    }
}

// ---------------------------------------------------------------------------
// wave w: rows [16w,16w+16) x 64 cols, 24 MFMAs (hi/lo), +bias -> oT.
// ---------------------------------------------------------------------------
__device__ __forceinline__ void dense_mfma(const short8_t ah0, const short8_t al0,
                                           const short8_t ah1, const short8_t al1,
                                           const short8_t* __restrict__ Bh,
                                           const short8_t* __restrict__ Bl,
                                           const float* __restrict__ bias,
                                           float* __restrict__ oT, int w,
                                           int lane) {
#pragma unroll 1
    for (int c = 0; c < 4; ++c) {
        short8_t bh0 = Bh[c * 64 + lane];
        short8_t bl0 = Bl[c * 64 + lane];
        short8_t bh1 = Bh[(4 + c) * 64 + lane];
        short8_t bl1 = Bl[(4 + c) * 64 + lane];
        f32x4 acc = {0.f, 0.f, 0.f, 0.f};
        acc = __builtin_amdgcn_mfma_f32_16x16x32_bf16(ah0, bh0, acc, 0, 0, 0);
        acc = __builtin_amdgcn_mfma_f32_16x16x32_bf16(al0, bh0, acc, 0, 0, 0);
        acc = __builtin_amdgcn_mfma_f32_16x16x32_bf16(ah0, bl0, acc, 0, 0, 0);
        acc = __builtin_amdgcn_mfma_f32_16x16x32_bf16(ah1, bh1, acc, 0, 0, 0);
        acc = __builtin_amdgcn_mfma_f32_16x16x32_bf16(al1, bh1, acc, 0, 0, 0);
        acc = __builtin_amdgcn_mfma_f32_16x16x32_bf16(ah1, bl1, acc, 0, 0, 0);
        int col = c * 16 + (lane & 15);
        float bb = bias[col];
#pragma unroll
        for (int r = 0; r < 4; ++r) {
            int row = w * 16 + ((lane >> 4) << 2) + r;
            oT[row * 64 + col] = acc[r] + bb;
        }
    }
}

// fixup: fj from LDS (broadcast reads), wk coalesced global vector loads.
__device__ __forceinline__ void fixup_pair_lds(const float* __restrict__ fj,
                                               const float* __restrict__ wk,
                                               float* __restrict__ oT, int row,
                                               int lane) {
    float a0 = 0.f, a1 = 0.f, a2 = 0.f, a3 = 0.f;
#pragma unroll
    for (int c4 = 0; c4 < 16; ++c4) {
        f32x4 fv = *(const f32x4*)(fj + c4 * 4);  // ds broadcast
        a0 += fv[0] * wk[(c4 * 4 + 0) * 64 + lane];
        a1 += fv[1] * wk[(c4 * 4 + 1) * 64 + lane];
        a2 += fv[2] * wk[(c4 * 4 + 2) * 64 + lane];
        a3 += fv[3] * wk[(c4 * 4 + 3) * 64 + lane];
    }
    atomicAdd(&oT[row * 64 + lane], (a0 + a1) + (a2 + a3));
}

// wave-scan helper (t<64): counts -> excl prefix + total, stored in LDS
__device__ __forceinline__ void scan64(int cnt, int lane, int* pfxs, int* cnts,
                                       int* nps) {
    int val = cnt;
#pragma unroll
    for (int off = 1; off < 64; off <<= 1) {
        int v2 = __shfl_up(val, off);
        if (lane >= off) val += v2;
    }
    pfxs[lane] = val - cnt;
    cnts[lane] = cnt;
    if (lane == 63) nps[0] = val;
}

// ---------------------------------------------------------------------------
// conv1 fused: 313 blocks x 256 thr. dense MFMA + scan -> compact -> staged
// fixups (chunks of 64) -> SiLU.
// ---------------------------------------------------------------------------
__global__ __launch_bounds__(256) void conv1_fused_kernel(
    const float* __restrict__ feats, const float* __restrict__ W1,
    const unsigned short* __restrict__ Wpk1h,
    const unsigned short* __restrict__ Wpk1l, const float* __restrict__ b1,
    const int* __restrict__ c1, const int* __restrict__ p1,
    float* __restrict__ h, int n) {
    __shared__ __align__(16) float oT[4096];
    __shared__ __align__(16) float fstage[64 * 64];
    __shared__ int pl[2048];
    __shared__ int pfxs[64], cnts_s[64], nps[1];
    int base = blockIdx.x * 64;
    int t = threadIdx.x, w = t >> 6, lane = t & 63;

    if (t < 64) {
        int cnt = (base + lane < n) ? c1[base + lane] : 0;
        scan64(cnt, lane, pfxs, cnts_s, nps);
    }

    int arow = base + w * 16 + (lane & 15);
    if (arow >= n) arow = n - 1;
    short8_t ah0, al0, ah1, al1;
    load_split_A(feats, arow, lane, ah0, al0, ah1, al1);
    dense_mfma(ah0, al0, ah1, al1, (const short8_t*)Wpk1h,
               (const short8_t*)Wpk1l, b1, oT, w, lane);
    __syncthreads();

    {   // parallel compaction: 4 threads per row
        int row = t & 63, e0 = t >> 6;
        int cr = cnts_s[row], pf = pfxs[row];
        for (int e = e0; e < cr; e += 4)
            pl[pf + e] = p1[(size_t)(base + row) * CAP1 + e] | (row << 23);
    }
    __syncthreads();

    int np = nps[0];
    for (int cb = 0; cb < np; cb += 64) {
        {   // stage: 4 threads per pair, 64B each, coalesced per row
            int p = cb + (t >> 2), qq = t & 3;
            if (p < np) {
                int j = pl[p] & 0x1FFFF;
                const f32x4* src = (const f32x4*)(feats + (size_t)j * 64 + qq * 16);
                f32x4* dst = (f32x4*)&fstage[(p - cb) * 64 + qq * 16];
#pragma unroll
                for (int q = 0; q < 4; ++q) dst[q] = src[q];
            }
        }
        __syncthreads();
        int pe = np < cb + 64 ? np : cb + 64;
#pragma unroll 1
        for (int p = cb + w; p < pe; p += 4) {
            int se = pl[p];
            int k = (se >> 17) & 31, row = (se >> 23) & 63;
            fixup_pair_lds(&fstage[(p - cb) * 64], W1 + (size_t)k * 4096, oT,
                           row, lane);
        }
        __syncthreads();
    }

    {   // SiLU + coalesced store
        int r = t >> 2, q0 = (t & 3) * 16;
        if (base + r < n) {
#pragma unroll
            for (int jj = 0; jj < 4; ++jj) {
                f32x4 v = *(f32x4*)&oT[r * 64 + q0 + jj * 4];
#pragma unroll
                for (int u = 0; u < 4; ++u) v[u] = v[u] / (1.f + __expf(-v[u]));
                *(f32x4*)&h[(size_t)(base + r) * 64 + q0 + jj * 4] = v;
            }
        }
    }
}

// ---------------------------------------------------------------------------
// conv2 fused: grid (313, 8). Same structure; chunks of 32 (LDS 26.5 KB).
// ---------------------------------------------------------------------------
__global__ __launch_bounds__(256) void conv2_fused_kernel(
    const float* __restrict__ h, const unsigned short* __restrict__ Wpk2h,
    const unsigned short* __restrict__ Wpk2l, const float* __restrict__ W2e,
    const float* __restrict__ b2, const int* __restrict__ c2s,
    const int* __restrict__ p2s, float* __restrict__ out, int n) {
    __shared__ __align__(16) float oT[4096];
    __shared__ __align__(16) float fstage[32 * 64];
    __shared__ int pl[512];
    __shared__ int pfxs[64], cnts_s[64], nps[1];
    int base = blockIdx.x * 64, s = blockIdx.y;
    int t = threadIdx.x, w = t >> 6, lane = t & 63;

    if (t < 64) {
        int cnt = (base + lane < n) ? c2s[(size_t)(base + lane) * 8 + s] : 0;
        scan64(cnt, lane, pfxs, cnts_s, nps);
    }

    int arow = base + w * 16 + (lane & 15);
    if (arow >= n) arow = n - 1;
    short8_t ah0, al0, ah1, al1;
    load_split_A(h, arow, lane, ah0, al0, ah1, al1);
    dense_mfma(ah0, al0, ah1, al1,
               (const short8_t*)Wpk2h + (size_t)s * 8 * 64,
               (const short8_t*)Wpk2l + (size_t)s * 8 * 64, b2, oT, w, lane);
    __syncthreads();

    {   // parallel compaction
        int row = t & 63, e0 = t >> 6;
        int cr = cnts_s[row], pf = pfxs[row];
        for (int e = e0; e < cr; e += 4)
            pl[pf + e] =
                p2s[((size_t)(base + row) * 8 + s) * CAP2S + e] | (row << 23);
    }
    __syncthreads();

    int np = nps[0];
    for (int cb = 0; cb < np; cb += 32) {
        {   // stage: 8 threads per pair, 32B each
            int p = cb + (t >> 3), qq = t & 7;
            if (p < np) {
                int j = pl[p] & 0x1FFFF;
                const f32x4* src = (const f32x4*)(h + (size_t)j * 64 + qq * 8);
                f32x4* dst = (f32x4*)&fstage[(p - cb) * 64 + qq * 8];
                dst[0] = src[0];
                dst[1] = src[1];
            }
        }
        __syncthreads();
        int pe = np < cb + 32 ? np : cb + 32;
#pragma unroll 1
        for (int p = cb + w; p < pe; p += 4) {
            int se = pl[p];
            int d = (se >> 17) & 31, row = (se >> 23) & 63;
            fixup_pair_lds(&fstage[(p - cb) * 64],
                           W2e + (size_t)(s * 8 + d) * 4096, oT, row, lane);
        }
        __syncthreads();
    }

    {   // SiLU + store (out row = parent*8 + s)
        int r = t >> 2, q0 = (t & 3) * 16;
        if (base + r < n) {
#pragma unroll
            for (int jj = 0; jj < 4; ++jj) {
                f32x4 v = *(f32x4*)&oT[r * 64 + q0 + jj * 4];
#pragma unroll
                for (int u = 0; u < 4; ++u) v[u] = v[u] / (1.f + __expf(-v[u]));
                *(f32x4*)&out[((size_t)(base + r) * 8 + s) * 64 + q0 + jj * 4] = v;
            }
        }
    }
}

// ---------------------------------------------------------------------------
extern "C" void kernel_launch(void* const* d_in, const int* in_sizes, int n_in,
                              void* d_out, int out_size, void* d_ws,
                              size_t ws_size, hipStream_t stream) {
    const int* coords = (const int*)d_in[0];
    const float* feats = (const float*)d_in[1];
    const float* W1 = (const float*)d_in[2];
    const float* b1 = (const float*)d_in[3];
    const float* W2 = (const float*)d_in[4];
    const float* b2 = (const float*)d_in[5];
    float* out = (float*)d_out;

    int n = in_sizes[0] / 3;  // 20000
    int nblk = (n + 63) / 64; // 313

    char* ws = (char*)d_ws;
    size_t off = 0;
    auto alloc = [&](size_t bytes) {
        size_t o = off;
        off = (off + bytes + 255) & ~(size_t)255;
        return o;
    };
    unsigned short* grid1 = (unsigned short*)(ws + alloc((size_t)GRID_VOX * 2));
    float* h      = (float*)(ws + alloc((size_t)n * 64 * 4));     // 5.12 MB
    float* W2e    = (float*)(ws + alloc(64 * 4096 * 4));          // 1 MB
    unsigned short* Wpk1h = (unsigned short*)(ws + alloc(512 * 8 * 2));
    unsigned short* Wpk1l = (unsigned short*)(ws + alloc(512 * 8 * 2));
    unsigned short* Wpk2h = (unsigned short*)(ws + alloc(4096 * 8 * 2));
    unsigned short* Wpk2l = (unsigned short*)(ws + alloc(4096 * 8 * 2));
    int*   c1     = (int*)(ws + alloc((size_t)n * 9 * 4));        // c1[n]+c2s[8n]
    int*   c2s    = c1 + n;
    int*   p1     = (int*)(ws + alloc((size_t)n * CAP1 * 4));     // 2.56 MB
    int*   p2s    = (int*)(ws + alloc((size_t)n * 8 * CAP2S * 4)); // 5.12 MB

    // setup: 432 grid-fill + 1042 weight-prep blocks
    setup_kernel<<<1474, 256, 0, stream>>>(W1, W2, (int4*)grid1, Wpk1h, Wpk1l,
                                           Wpk2h, Wpk2l, W2e);
    scatter_grid_kernel<<<(n + 255) / 256, 256, 0, stream>>>(coords, grid1, n);
    build_pairs_kernel<<<(n + 255) / 256, 256, 0, stream>>>(
        coords, grid1, c1, p1, c2s, p2s, n);

    conv1_fused_kernel<<<nblk, 256, 0, stream>>>(feats, W1, Wpk1h, Wpk1l, b1,
                                                 c1, p1, h, n);
    conv2_fused_kernel<<<dim3(nblk, 8), 256, 0, stream>>>(
        h, Wpk2h, Wpk2l, W2e, b2, c2s, p2s, out, n);
}